// Round 5
// baseline (2547.888 us; speedup 1.0000x reference)
//
#include <hip/hip_runtime.h>

// ---------------- sizes / workspace layout (floats) ----------------
constexpr int BB   = 16;
constexpr int VS   = BB*3*32*32;     // 49152
constexpr int M1N  = BB*64*32*32;    // 1048576
constexpr int O1PN = BB*64*18*20;    // 368640 (padded 16x16 interior)
constexpr int M2N  = BB*128*16*16;   // 524288
constexpr int O2PN = BB*128*18*20;   // 737280
constexpr int M3N  = M2N;
constexpr int FBN  = BB*8192;        // 131072
constexpr int M4N  = BB*1024;
constexpr int M5N  = BB*1024;

constexpr int off_v   = 0;                 // x2 ping-pong
constexpr int off_s   = off_v   + 2*VS;
constexpr int off_m1  = off_s   + 2*VS;
constexpr int off_o1p = off_m1  + M1N;     // x2
constexpr int off_m2  = off_o1p + 2*O1PN;
constexpr int off_o2p = off_m2  + M2N;     // x2
constexpr int off_m3  = off_o2p + 2*O2PN;
constexpr int off_f   = off_m3  + M3N;     // x2
constexpr int off_m4  = off_f   + 2*FBN;
constexpr int off_o4  = off_m4  + M4N;     // x2
constexpr int off_m5  = off_o4  + 2*M4N;
constexpr int off_o5  = off_m5  + M5N;     // x2
constexpr int off_w1r = off_o5  + 2*M5N;   // zero-region ends here
constexpr int W1RN = 64*3*12;              // conv1: [co][ci][12]
constexpr int off_w2r = off_w1r + W1RN;
constexpr int W2RN = 128*64*12;            // conv2: [co][ci][12]
constexpr int off_w3r = off_w2r + W2RN;
constexpr int W3RN = 128*128*12;           // conv3: [co][ci][12]
constexpr int TOTF = off_w3r + W3RN;

__device__ __forceinline__ float4 ld4(const float* p){ return *reinterpret_cast<const float4*>(p); }
__device__ __forceinline__ float2 ld2(const float* p){ return *reinterpret_cast<const float2*>(p); }
__device__ __forceinline__ float spk(float m){ return m > 1.0f ? 1.0f : 0.0f; }

// ---------------- init: zero state, repack conv weights to [co][ci][12] ----------------
__global__ __launch_bounds__(256) void init_k(const float* __restrict__ W1,
                                              const float* __restrict__ W2,
                                              const float* __restrict__ W3,
                                              float* __restrict__ ws,
                                              float* __restrict__ out) {
    int i0 = blockIdx.x*256 + threadIdx.x;
    int stride = gridDim.x*256;
    for (int p = i0; p < TOTF; p += stride) {
        float val = 0.0f;
        if (p >= off_w1r) {
            int q, r; const float* src;
            if (p < off_w2r)      { int l = p - off_w1r; q = l/12; r = l%12; src = W1; }
            else if (p < off_w3r) { int l = p - off_w2r; q = l/12; r = l%12; src = W2; }
            else                  { int l = p - off_w3r; q = l/12; r = l%12; src = W3; }
            int dx = r & 3, dy = r >> 2;
            val = (dx < 3) ? src[q*9 + dy*3 + dx] : 0.0f;
        }
        ws[p] = val;
    }
    if (i0 < 160) out[i0] = 0.0f;
}

// ---------------- one fused timestep ----------------
// bid map: [0,256) conv3 | [256,512) conv2 | [512,768) enc+conv1
//          [768,896) fc1 | [896,1152) fc2 | 1152 fc3
__global__ __launch_bounds__(256) void step_k(const float* __restrict__ x,
                                              const float* __restrict__ L1,
                                              const float* __restrict__ L2,
                                              const float* __restrict__ L3,
                                              float* __restrict__ ws,
                                              float* __restrict__ out,
                                              int t) {
    const int rp = t & 1, wp = rp ^ 1;
    const int bid = blockIdx.x, tid = threadIdx.x;
    __shared__ float sh[8448];   // fc1 dbuf 2x4096 + reduction 4x2112; fc2 4608; conv1 360

    if (bid < 256) {
        // ---- conv3 (128->128) + LIF(m3) + pool: 256 blocks x 8 co, 2 co/lane ----
        int b = bid >> 4, cog = bid & 15;
        int pair = tid >> 6, l = tid & 63;
        int ry = l >> 2, xc = (l & 3)*4;
        int co0 = cog*8 + pair*2;
        const float* ip  = ws + off_o2p + rp*O2PN + b*128*360 + ry*20 + xc;
        const float* wt0 = ws + off_w3r + co0*1536;
        const float* wt1 = wt0 + 1536;
        float acc[2][4] = {};
        float4 nu[3]; float2 nv[3]; float4 nwa[3], nwb[3];
        #pragma unroll
        for (int r = 0; r < 3; ++r) {
            nu[r] = ld4(ip + r*20); nv[r] = ld2(ip + r*20 + 4);
            nwa[r] = ld4(wt0 + r*4); nwb[r] = ld4(wt1 + r*4);
        }
        for (int ci = 0; ci < 128; ++ci) {
            float4 cu[3]; float2 cv[3]; float4 wa[3], wb2[3];
            #pragma unroll
            for (int r = 0; r < 3; ++r) { cu[r]=nu[r]; cv[r]=nv[r]; wa[r]=nwa[r]; wb2[r]=nwb[r]; }
            if (ci < 127) {
                const float* rn = ip + (ci + 1)*360;
                const float* w0n = wt0 + (ci + 1)*12;
                const float* w1n = wt1 + (ci + 1)*12;
                #pragma unroll
                for (int r = 0; r < 3; ++r) {
                    nu[r] = ld4(rn + r*20); nv[r] = ld2(rn + r*20 + 4);
                    nwa[r] = ld4(w0n + r*4); nwb[r] = ld4(w1n + r*4);
                }
            }
            float rv[3][6];
            #pragma unroll
            for (int r = 0; r < 3; ++r) {
                rv[r][0]=cu[r].x; rv[r][1]=cu[r].y; rv[r][2]=cu[r].z; rv[r][3]=cu[r].w;
                rv[r][4]=cv[r].x; rv[r][5]=cv[r].y;
            }
            float wd[2][3][3] = {{{wa[0].x,wa[0].y,wa[0].z},{wa[1].x,wa[1].y,wa[1].z},{wa[2].x,wa[2].y,wa[2].z}},
                                 {{wb2[0].x,wb2[0].y,wb2[0].z},{wb2[1].x,wb2[1].y,wb2[1].z},{wb2[2].x,wb2[2].y,wb2[2].z}}};
            #pragma unroll
            for (int cc = 0; cc < 2; ++cc)
                #pragma unroll
                for (int dy = 0; dy < 3; ++dy)
                    #pragma unroll
                    for (int dx = 0; dx < 3; ++dx) {
                        float wvv = wd[cc][dy][dx];
                        #pragma unroll
                        for (int p = 0; p < 4; ++p) acc[cc][p] += rv[dy][p+dx]*wvv;
                    }
        }
        #pragma unroll
        for (int cc = 0; cc < 2; ++cc) {
            int co = co0 + cc;
            float* mp = ws + off_m3 + (((b*128 + co)*16 + ry)*16 + xc);
            float4 mv = ld4(mp);
            float mm[4] = {mv.x, mv.y, mv.z, mv.w};
            float sp[4];
            #pragma unroll
            for (int p = 0; p < 4; ++p) {
                float o = spk(mm[p]);
                float mn = mm[p] + acc[cc][p] - o;
                mm[p] = mn; sp[p] = spk(mn);
            }
            *reinterpret_cast<float4*>(mp) = make_float4(mm[0], mm[1], mm[2], mm[3]);
            float s01 = sp[0] + sp[1], s23 = sp[2] + sp[3];
            float o01 = __shfl_xor(s01, 4, 64);
            float o23 = __shfl_xor(s23, 4, 64);
            if ((ry & 1) == 0) {
                int fbase = off_f + wp*FBN + b*8192 + co*64 + (ry>>1)*8 + (xc>>1);
                ws[fbase]     = (s01 + o01)*0.25f;
                ws[fbase + 1] = (s23 + o23)*0.25f;
            }
        }
    } else if (bid < 512) {
        // ---- conv2 (64->128) + LIF(m2): 256 blocks x 8 co, 2 co/lane ----
        int bb = bid - 256, b = bb >> 4, cog = bb & 15;
        int pair = tid >> 6, l = tid & 63;
        int ry = l >> 2, xc = (l & 3)*4;
        int co0 = cog*8 + pair*2;
        const float* ip  = ws + off_o1p + rp*O1PN + b*64*360 + ry*20 + xc;
        const float* wt0 = ws + off_w2r + co0*768;
        const float* wt1 = wt0 + 768;
        float acc[2][4] = {};
        float4 nu[3]; float2 nv[3]; float4 nwa[3], nwb[3];
        #pragma unroll
        for (int r = 0; r < 3; ++r) {
            nu[r] = ld4(ip + r*20); nv[r] = ld2(ip + r*20 + 4);
            nwa[r] = ld4(wt0 + r*4); nwb[r] = ld4(wt1 + r*4);
        }
        for (int ci = 0; ci < 64; ++ci) {
            float4 cu[3]; float2 cv[3]; float4 wa[3], wb2[3];
            #pragma unroll
            for (int r = 0; r < 3; ++r) { cu[r]=nu[r]; cv[r]=nv[r]; wa[r]=nwa[r]; wb2[r]=nwb[r]; }
            if (ci < 63) {
                const float* rn = ip + (ci + 1)*360;
                const float* w0n = wt0 + (ci + 1)*12;
                const float* w1n = wt1 + (ci + 1)*12;
                #pragma unroll
                for (int r = 0; r < 3; ++r) {
                    nu[r] = ld4(rn + r*20); nv[r] = ld2(rn + r*20 + 4);
                    nwa[r] = ld4(w0n + r*4); nwb[r] = ld4(w1n + r*4);
                }
            }
            float rv[3][6];
            #pragma unroll
            for (int r = 0; r < 3; ++r) {
                rv[r][0]=cu[r].x; rv[r][1]=cu[r].y; rv[r][2]=cu[r].z; rv[r][3]=cu[r].w;
                rv[r][4]=cv[r].x; rv[r][5]=cv[r].y;
            }
            float wd[2][3][3] = {{{wa[0].x,wa[0].y,wa[0].z},{wa[1].x,wa[1].y,wa[1].z},{wa[2].x,wa[2].y,wa[2].z}},
                                 {{wb2[0].x,wb2[0].y,wb2[0].z},{wb2[1].x,wb2[1].y,wb2[1].z},{wb2[2].x,wb2[2].y,wb2[2].z}}};
            #pragma unroll
            for (int cc = 0; cc < 2; ++cc)
                #pragma unroll
                for (int dy = 0; dy < 3; ++dy)
                    #pragma unroll
                    for (int dx = 0; dx < 3; ++dx) {
                        float wvv = wd[cc][dy][dx];
                        #pragma unroll
                        for (int p = 0; p < 4; ++p) acc[cc][p] += rv[dy][p+dx]*wvv;
                    }
        }
        #pragma unroll
        for (int cc = 0; cc < 2; ++cc) {
            int co = co0 + cc;
            float* mp = ws + off_m2 + (((b*128 + co)*16 + ry)*16 + xc);
            float4 mv = ld4(mp);
            float mm[4] = {mv.x, mv.y, mv.z, mv.w};
            int obase = off_o2p + wp*O2PN + ((b*128 + co)*18 + ry + 1)*20 + xc + 1;
            #pragma unroll
            for (int p = 0; p < 4; ++p) {
                float o = spk(mm[p]);
                float mn = mm[p] + acc[cc][p] - o;
                mm[p] = mn;
                ws[obase + p] = spk(mn);
            }
            *reinterpret_cast<float4*>(mp) = make_float4(mm[0], mm[1], mm[2], mm[3]);
        }
    } else if (bid < 768) {
        // ---- encoder (redundant) + conv1 + LIF(m1) + pooled next-spike ----
        int bb = bid - 512;
        int b = bb >> 4, tile = bb & 15;
        int ty = tile >> 2, tx = tile & 3;
        int y0 = ty*8, x0 = tx*8;
        const float* vin  = ws + off_v + rp*VS + b*3072;
        float*       vout = ws + off_v + wp*VS + b*3072;
        const float* sin_ = ws + off_s + rp*VS + b*3072;
        float*       sout = ws + off_s + wp*VS + b*3072;
        const float* xin  = x + b*3072;
        float* sl = sh; // [3][10][12]
        for (int idx = tid; idx < 300; idx += 256) {
            int ci = idx/100, r2 = idx%100, rr = r2/10, cc = r2%10;
            int yy = y0 - 1 + rr, xx = x0 - 1 + cc;
            float sv = 0.0f;
            if ((unsigned)yy < 32u && (unsigned)xx < 32u) {
                int g = ci*1024 + yy*32 + xx;
                float vn = vin[g] + xin[g] - sin_[g];
                sv = vn > 1.0f ? 1.0f : 0.0f;
                if (yy >= y0 && yy < y0+8 && xx >= x0 && xx < x0+8) { vout[g] = vn; sout[g] = sv; }
            }
            sl[(ci*10 + rr)*12 + cc] = sv;
        }
        __syncthreads();
        int tl = tid & 15, cog = tid >> 4;
        int py = (tl >> 2)*2, px = (tl & 3)*2;
        for (int cl = 0; cl < 4; ++cl) {
            int co = cog*4 + cl;
            const float* wtp = ws + off_w1r + co*36;
            float a00=0,a01=0,a10=0,a11=0;
            #pragma unroll
            for (int ci = 0; ci < 3; ++ci) {
                float4 w0 = ld4(wtp + ci*12), w1 = ld4(wtp + ci*12 + 4), w2 = ld4(wtp + ci*12 + 8);
                float wdl[3][3] = {{w0.x,w0.y,w0.z},{w1.x,w1.y,w1.z},{w2.x,w2.y,w2.z}};
                #pragma unroll
                for (int dy = 0; dy < 3; ++dy)
                    #pragma unroll
                    for (int dx = 0; dx < 3; ++dx) {
                        float wvv = wdl[dy][dx];
                        const float* rsl = sl + (ci*10 + py + dy)*12 + px + dx;
                        a00 += rsl[0]  * wvv; a01 += rsl[1]  * wvv;
                        a10 += rsl[12] * wvv; a11 += rsl[13] * wvv;
                    }
            }
            int gy = y0 + py, gx = x0 + px;
            float accs[2][2] = {{a00,a01},{a10,a11}};
            float pooled = 0.0f;
            #pragma unroll
            for (int iy = 0; iy < 2; ++iy)
                #pragma unroll
                for (int ix = 0; ix < 2; ++ix) {
                    int gm = off_m1 + ((b*64 + co)*32 + gy + iy)*32 + gx + ix;
                    float m = ws[gm], o = spk(m);
                    float mn = m + accs[iy][ix] - o;
                    ws[gm] = mn;
                    pooled += spk(mn);
                }
            ws[off_o1p + wp*O1PN + ((b*64 + co)*18 + (gy>>1) + 1)*20 + (gx>>1) + 1] = pooled*0.25f;
        }
    } else if (bid < 896) {
        // ---- fc1 8192->1024 + LIF(m4): 128 blocks x 8 j; LDS dbuf acts, 2-deep W prefetch ----
        int jb = bid - 768;
        int w = tid >> 6, l = tid & 63;
        const float* fp = ws + off_f + rp*FBN;
        const float* wb = L1 + (jb*8 + w*2)*8192;
        float acc[2][16] = {};
        float4 wA[2], wB[2];
        #pragma unroll
        for (int jj = 0; jj < 2; ++jj) {
            wA[jj] = ld4(wb + jj*8192 + l*4);
            wB[jj] = ld4(wb + jj*8192 + 256 + l*4);
        }
        #pragma unroll
        for (int q = 0; q < 4; ++q) {
            int i4 = q*256 + tid; int b = i4 >> 6, kk = (i4 & 63)*4;
            *reinterpret_cast<float4*>(sh + i4*4) = ld4(fp + b*8192 + kk);
        }
        __syncthreads();
        for (int c = 0; c < 32; ++c) {
            int cur = (c & 1)*4096, nxt = 4096 - cur;
            if (c < 31) {
                #pragma unroll
                for (int q = 0; q < 4; ++q) {
                    int i4 = q*256 + tid; int b = i4 >> 6, kk = (i4 & 63)*4;
                    *reinterpret_cast<float4*>(sh + nxt + i4*4) = ld4(fp + b*8192 + (c+1)*256 + kk);
                }
            }
            #pragma unroll
            for (int b = 0; b < 16; ++b) {
                float4 fv = *reinterpret_cast<const float4*>(sh + cur + b*256 + l*4);
                acc[0][b] += wA[0].x*fv.x + wA[0].y*fv.y + wA[0].z*fv.z + wA[0].w*fv.w;
                acc[1][b] += wA[1].x*fv.x + wA[1].y*fv.y + wA[1].z*fv.z + wA[1].w*fv.w;
            }
            wA[0] = wB[0]; wA[1] = wB[1];
            if (c < 30) {
                wB[0] = ld4(wb + (c+2)*256 + l*4);
                wB[1] = ld4(wb + 8192 + (c+2)*256 + l*4);
            }
            __syncthreads();
        }
        // per-wave 64-lane reduction, stride-33 (conflict-free)
        float* rg = sh + w*2112;
        #pragma unroll
        for (int jj = 0; jj < 2; ++jj)
            #pragma unroll
            for (int b = 0; b < 16; ++b) rg[l*33 + jj*16 + b] = acc[jj][b];
        __syncthreads();
        if (tid < 128) {
            int w2 = tid >> 5, r = tid & 31, jj = r >> 4, b = r & 15;
            const float* rg2 = sh + w2*2112;
            float sum = 0.0f;
            for (int l2 = 0; l2 < 64; ++l2) sum += rg2[l2*33 + r];
            int j = jb*8 + w2*2 + jj;
            int gi = off_m4 + b*1024 + j;
            float m = ws[gi], o = spk(m);
            float mn = m + sum - o;
            ws[gi] = mn;
            ws[off_o4 + wp*M4N + b*1024 + j] = spk(mn);
        }
    } else if (bid < 1152) {
        // ---- fc2 1024->1024 + LIF(m5); 256 blocks x 4 cols, 64-lane K-split ----
        int jb = bid - 896;
        int jg = tid >> 6, l = tid & 63;
        int j  = jb*4 + jg;
        const float* op = ws + off_o4 + rp*M4N;
        const float* wr = L2 + j*1024;
        float acc[16] = {};
        float4 wv[4];
        #pragma unroll
        for (int u = 0; u < 4; ++u) wv[u] = ld4(wr + u*256 + l*4);
        #pragma unroll
        for (int u = 0; u < 4; ++u) {
            int k = u*256 + l*4;
            #pragma unroll
            for (int b = 0; b < 16; ++b) {
                float4 fv = ld4(op + b*1024 + k);
                acc[b] += wv[u].x*fv.x + wv[u].y*fv.y + wv[u].z*fv.z + wv[u].w*fv.w;
            }
        }
        int r = jg*64 + l;
        #pragma unroll
        for (int b = 0; b < 16; ++b) sh[r*17 + b] = acc[b];
        __syncthreads();
        {
            int p = tid >> 2, q = tid & 3;
            float s2 = 0.0f;
            int rb2 = (p >> 4)*64 + q*16, col = p & 15;
            #pragma unroll
            for (int t2 = 0; t2 < 16; ++t2) s2 += sh[(rb2 + t2)*17 + col];
            sh[4352 + tid] = s2;
        }
        __syncthreads();
        if (tid < 64) {
            float sum = sh[4352 + tid*4] + sh[4352 + tid*4 + 1]
                      + sh[4352 + tid*4 + 2] + sh[4352 + tid*4 + 3];
            int jg2 = tid >> 4, b = tid & 15;
            int jj = jb*4 + jg2;
            int gi = off_m5 + b*1024 + jj;
            float m = ws[gi], o = spk(m);
            float mn = m + sum - o;
            ws[gi] = mn;
            ws[off_o5 + wp*M5N + b*1024 + jj] = spk(mn);
        }
    } else {
        // ---- fc3 1024->10, accumulate output membrane ----
        if (tid < 160) {
            int b = tid/10, c = tid - b*10;
            const float* op = ws + off_o5 + rp*M5N + b*1024;
            const float* wr = L3 + c*1024;
            float sum = 0.0f;
            for (int k = 0; k < 1024; k += 4) {
                float4 a = ld4(op + k), wvv = ld4(wr + k);
                sum += a.x*wvv.x + a.y*wvv.y + a.z*wvv.z + a.w*wvv.w;
            }
            out[b*10 + c] += sum;
        }
    }
}

extern "C" void kernel_launch(void* const* d_in, const int* in_sizes, int n_in,
                              void* d_out, int out_size, void* d_ws, size_t ws_size,
                              hipStream_t stream) {
    const float* x  = (const float*)d_in[0];
    const float* W1 = (const float*)d_in[1];
    const float* W2 = (const float*)d_in[2];
    const float* W3 = (const float*)d_in[3];
    const float* L1 = (const float*)d_in[4];
    const float* L2 = (const float*)d_in[5];
    const float* L3 = (const float*)d_in[6];
    float* out = (float*)d_out;
    float* ws  = (float*)d_ws;

    init_k<<<1024, 256, 0, stream>>>(W1, W2, W3, ws, out);
    for (int t = 0; t < 20; ++t)
        step_k<<<1153, 256, 0, stream>>>(x, L1, L2, L3, ws, out, t);
}

// Round 6
// 1858.149 us; speedup vs baseline: 1.3712x; 1.3712x over previous
//
#include <hip/hip_runtime.h>

// ---------------- sizes / workspace layout (floats) ----------------
constexpr int BB   = 16;
constexpr int VS   = BB*3*32*32;     // 49152
constexpr int M1N  = BB*64*32*32;    // 1048576
constexpr int O1PN = BB*64*18*20;    // 368640 (padded 16x16 interior)
constexpr int M2N  = BB*128*16*16;   // 524288
constexpr int O2PN = BB*128*18*20;   // 737280
constexpr int M3N  = M2N;
constexpr int FBN  = BB*8192;        // 131072
constexpr int M4N  = BB*1024;
constexpr int M5N  = BB*1024;

constexpr int off_v   = 0;                 // x2 ping-pong
constexpr int off_s   = off_v   + 2*VS;
constexpr int off_m1  = off_s   + 2*VS;
constexpr int off_o1p = off_m1  + M1N;     // x2
constexpr int off_m2  = off_o1p + 2*O1PN;
constexpr int off_o2p = off_m2  + M2N;     // x2
constexpr int off_m3  = off_o2p + 2*O2PN;
constexpr int off_f   = off_m3  + M3N;     // x2
constexpr int off_m4  = off_f   + 2*FBN;
constexpr int off_o4  = off_m4  + M4N;     // x2
constexpr int off_m5  = off_o4  + 2*M4N;
constexpr int off_o5  = off_m5  + M5N;     // x2
constexpr int off_w1r = off_o5  + 2*M5N;   // zero-region ends here
constexpr int W1RN = 64*3*12;              // conv1: [co][ci][12]
constexpr int off_w2r = off_w1r + W1RN;
constexpr int W2RN = 8*64*256;             // conv2: [cog8][ci64][c16][16]
constexpr int off_w3r = off_w2r + W2RN;
constexpr int W3RN = 8*128*256;            // conv3: [cog8][ci128][c16][16]
constexpr int TOTF = off_w3r + W3RN;

__device__ __forceinline__ float4 ld4(const float* p){ return *reinterpret_cast<const float4*>(p); }
__device__ __forceinline__ float2 ld2(const float* p){ return *reinterpret_cast<const float2*>(p); }
__device__ __forceinline__ float spk(float m){ return m > 1.0f ? 1.0f : 0.0f; }

// ---------------- init: zero state, repack conv weights ----------------
__global__ __launch_bounds__(256) void init_k(const float* __restrict__ W1,
                                              const float* __restrict__ W2,
                                              const float* __restrict__ W3,
                                              float* __restrict__ ws,
                                              float* __restrict__ out) {
    int i0 = blockIdx.x*256 + threadIdx.x;
    int stride = gridDim.x*256;
    for (int p = i0; p < TOTF; p += stride) {
        float val = 0.0f;
        if (p >= off_w1r) {
            if (p < off_w2r) {               // conv1 [co][ci][12]
                int l = p - off_w1r, q = l/12, r = l%12;
                int dx = r & 3, dy = r >> 2;
                val = (dx < 3) ? W1[q*9 + dy*3 + dx] : 0.0f;
            } else if (p < off_w3r) {        // conv2 [cog][ci][c16][16]
                int l = p - off_w2r;
                int cog = l >> 14, rem = l & 16383;
                int ci = rem >> 8, rem2 = rem & 255, c16 = rem2 >> 4, r = rem2 & 15;
                int dy = r >> 2, dx = r & 3;
                int co = cog*16 + c16;
                val = (r < 12 && dx < 3) ? W2[(co*64 + ci)*9 + dy*3 + dx] : 0.0f;
            } else {                         // conv3 [cog][ci][c16][16]
                int l = p - off_w3r;
                int cog = l >> 15, rem = l & 32767;
                int ci = rem >> 8, rem2 = rem & 255, c16 = rem2 >> 4, r = rem2 & 15;
                int dy = r >> 2, dx = r & 3;
                int co = cog*16 + c16;
                val = (r < 12 && dx < 3) ? W3[(co*128 + ci)*9 + dy*3 + dx] : 0.0f;
            }
        }
        ws[p] = val;
    }
    if (i0 < 160) out[i0] = 0.0f;
}

// ---------------- one fused timestep ----------------
// bid map (longest blocks first): [0,128) conv3 | [128,256) conv2 | [256,384) fc1
//          [384,640) enc+conv1 | [640,896) fc2 | 896 fc3
__global__ __launch_bounds__(256) void step_k(const float* __restrict__ x,
                                              const float* __restrict__ L1,
                                              const float* __restrict__ L2,
                                              const float* __restrict__ L3,
                                              float* __restrict__ ws,
                                              float* __restrict__ out,
                                              int t) {
    const int rp = t & 1, wp = rp ^ 1;
    const int bid = blockIdx.x, tid = threadIdx.x;
    __shared__ float sh[8448];   // conv weights 8192 | fc1 dbuf 2x4096 + reduce 4x2112 | fc2 4608

    if (bid < 128) {
        // ---- conv3 (128->128) + LIF(m3) + pool: 128 blocks x 16 co, 2 co/lane, LDS weights ----
        int bb = bid, b = bb >> 3, cog = bb & 7;
        int cl = tid >> 5, rest = tid & 31, rpair = rest >> 2, cg = rest & 3;
        int y0 = rpair*2, x0 = cg*4;
        const float* ip = ws + off_o2p + rp*O2PN + b*128*360 + y0*20 + x0;
        const float* gw = ws + off_w3r + cog*32768;
        float acc[2][2][4] = {};
        float4 nu[4]; float2 nv[4];
        #pragma unroll
        for (int r = 0; r < 4; ++r) { nu[r] = ld4(ip + r*20); nv[r] = ld2(ip + r*20 + 4); }
        for (int ch = 0; ch < 4; ++ch) {
            __syncthreads();
            #pragma unroll
            for (int q = 0; q < 8; ++q) {
                int i4 = q*256 + tid;                 // 0..2047 float4s
                *reinterpret_cast<float4*>(sh + i4*4) = ld4(gw + ch*8192 + i4*4);
            }
            __syncthreads();
            for (int cil = 0; cil < 32; ++cil) {
                int ci = ch*32 + cil;
                float4 cu[4]; float2 cv[4];
                #pragma unroll
                for (int r = 0; r < 4; ++r) { cu[r] = nu[r]; cv[r] = nv[r]; }
                if (ci < 127) {
                    const float* rn = ip + (ci + 1)*360;
                    #pragma unroll
                    for (int r = 0; r < 4; ++r) { nu[r] = ld4(rn + r*20); nv[r] = ld2(rn + r*20 + 4); }
                }
                const float* wp0 = sh + cil*256 + cl*32;
                float4 a0 = *reinterpret_cast<const float4*>(wp0);
                float4 a1 = *reinterpret_cast<const float4*>(wp0 + 4);
                float4 a2 = *reinterpret_cast<const float4*>(wp0 + 8);
                float4 b0 = *reinterpret_cast<const float4*>(wp0 + 16);
                float4 b1 = *reinterpret_cast<const float4*>(wp0 + 20);
                float4 b2 = *reinterpret_cast<const float4*>(wp0 + 24);
                float wd[2][3][3] = {{{a0.x,a0.y,a0.z},{a1.x,a1.y,a1.z},{a2.x,a2.y,a2.z}},
                                     {{b0.x,b0.y,b0.z},{b1.x,b1.y,b1.z},{b2.x,b2.y,b2.z}}};
                float rv[4][6];
                #pragma unroll
                for (int r = 0; r < 4; ++r) {
                    rv[r][0]=cu[r].x; rv[r][1]=cu[r].y; rv[r][2]=cu[r].z; rv[r][3]=cu[r].w;
                    rv[r][4]=cv[r].x; rv[r][5]=cv[r].y;
                }
                #pragma unroll
                for (int cc = 0; cc < 2; ++cc)
                    #pragma unroll
                    for (int iy = 0; iy < 2; ++iy)
                        #pragma unroll
                        for (int dy = 0; dy < 3; ++dy) {
                            int r = iy + dy;
                            #pragma unroll
                            for (int dx = 0; dx < 3; ++dx) {
                                float wvv = wd[cc][dy][dx];
                                #pragma unroll
                                for (int p = 0; p < 4; ++p) acc[cc][iy][p] += rv[r][p+dx]*wvv;
                            }
                        }
            }
        }
        #pragma unroll
        for (int cc = 0; cc < 2; ++cc) {
            int co = cog*16 + cl*2 + cc;
            float sp[2][4];
            #pragma unroll
            for (int iy = 0; iy < 2; ++iy)
                #pragma unroll
                for (int p = 0; p < 4; ++p) {
                    int gm = off_m3 + ((b*128 + co)*16 + y0 + iy)*16 + x0 + p;
                    float m = ws[gm], o = spk(m);
                    float mn = m + acc[cc][iy][p] - o;
                    ws[gm] = mn;
                    sp[iy][p] = spk(mn);
                }
            int fbase = off_f + wp*FBN + b*8192 + co*64 + (y0>>1)*8 + (x0>>1);
            ws[fbase+0] = (sp[0][0]+sp[0][1]+sp[1][0]+sp[1][1])*0.25f;
            ws[fbase+1] = (sp[0][2]+sp[0][3]+sp[1][2]+sp[1][3])*0.25f;
        }
    } else if (bid < 256) {
        // ---- conv2 (64->128) + LIF(m2): 128 blocks x 16 co, 2 co/lane, LDS weights ----
        int bb = bid - 128, b = bb >> 3, cog = bb & 7;
        int cl = tid >> 5, rest = tid & 31, y = rest >> 1, x0 = (rest & 1)*8;
        const float* ip = ws + off_o1p + rp*O1PN + b*64*360 + y*20 + x0;
        const float* gw = ws + off_w2r + cog*16384;
        float acc[2][8] = {};
        float4 nr[3], ns[3]; float2 nt2[3];
        #pragma unroll
        for (int dy = 0; dy < 3; ++dy) {
            nr[dy] = ld4(ip + dy*20); ns[dy] = ld4(ip + dy*20 + 4); nt2[dy] = ld2(ip + dy*20 + 8);
        }
        for (int ch = 0; ch < 2; ++ch) {
            __syncthreads();
            #pragma unroll
            for (int q = 0; q < 8; ++q) {
                int i4 = q*256 + tid;
                *reinterpret_cast<float4*>(sh + i4*4) = ld4(gw + ch*8192 + i4*4);
            }
            __syncthreads();
            for (int cil = 0; cil < 32; ++cil) {
                int ci = ch*32 + cil;
                float4 cr[3], cs[3]; float2 ct[3];
                #pragma unroll
                for (int dy = 0; dy < 3; ++dy) { cr[dy] = nr[dy]; cs[dy] = ns[dy]; ct[dy] = nt2[dy]; }
                if (ci < 63) {
                    const float* rn = ip + (ci + 1)*360;
                    #pragma unroll
                    for (int dy = 0; dy < 3; ++dy) {
                        nr[dy] = ld4(rn + dy*20); ns[dy] = ld4(rn + dy*20 + 4); nt2[dy] = ld2(rn + dy*20 + 8);
                    }
                }
                const float* wp0 = sh + cil*256 + cl*32;
                float4 a0 = *reinterpret_cast<const float4*>(wp0);
                float4 a1 = *reinterpret_cast<const float4*>(wp0 + 4);
                float4 a2 = *reinterpret_cast<const float4*>(wp0 + 8);
                float4 b0 = *reinterpret_cast<const float4*>(wp0 + 16);
                float4 b1 = *reinterpret_cast<const float4*>(wp0 + 20);
                float4 b2 = *reinterpret_cast<const float4*>(wp0 + 24);
                float wd[2][3][3] = {{{a0.x,a0.y,a0.z},{a1.x,a1.y,a1.z},{a2.x,a2.y,a2.z}},
                                     {{b0.x,b0.y,b0.z},{b1.x,b1.y,b1.z},{b2.x,b2.y,b2.z}}};
                #pragma unroll
                for (int dy = 0; dy < 3; ++dy) {
                    float rv[10] = {cr[dy].x,cr[dy].y,cr[dy].z,cr[dy].w,
                                    cs[dy].x,cs[dy].y,cs[dy].z,cs[dy].w,
                                    ct[dy].x,ct[dy].y};
                    #pragma unroll
                    for (int cc = 0; cc < 2; ++cc)
                        #pragma unroll
                        for (int dx = 0; dx < 3; ++dx) {
                            float wvv = wd[cc][dy][dx];
                            #pragma unroll
                            for (int p = 0; p < 8; ++p) acc[cc][p] += rv[p+dx]*wvv;
                        }
                }
            }
        }
        #pragma unroll
        for (int cc = 0; cc < 2; ++cc) {
            int co = cog*16 + cl*2 + cc;
            int mbase = off_m2 + ((b*128 + co)*16 + y)*16 + x0;
            int obase = off_o2p + wp*O2PN + ((b*128 + co)*18 + y + 1)*20 + x0 + 1;
            #pragma unroll
            for (int p = 0; p < 8; ++p) {
                float m = ws[mbase+p], o = spk(m);
                float mn = m + acc[cc][p] - o;
                ws[mbase+p] = mn;
                ws[obase+p] = spk(mn);
            }
        }
    } else if (bid < 384) {
        // ---- fc1 8192->1024 + LIF(m4): 128 blocks x 8 j; LDS dbuf acts, 2-deep W prefetch ----
        int jb = bid - 256;
        int w = tid >> 6, l = tid & 63;
        const float* fp = ws + off_f + rp*FBN;
        const float* wb = L1 + (jb*8 + w*2)*8192;
        float acc[2][16] = {};
        float4 wA[2], wB[2];
        #pragma unroll
        for (int jj = 0; jj < 2; ++jj) {
            wA[jj] = ld4(wb + jj*8192 + l*4);
            wB[jj] = ld4(wb + jj*8192 + 256 + l*4);
        }
        #pragma unroll
        for (int q = 0; q < 4; ++q) {
            int i4 = q*256 + tid; int b = i4 >> 6, kk = (i4 & 63)*4;
            *reinterpret_cast<float4*>(sh + i4*4) = ld4(fp + b*8192 + kk);
        }
        __syncthreads();
        for (int c = 0; c < 32; ++c) {
            int cur = (c & 1)*4096, nxt = 4096 - cur;
            if (c < 31) {
                #pragma unroll
                for (int q = 0; q < 4; ++q) {
                    int i4 = q*256 + tid; int b = i4 >> 6, kk = (i4 & 63)*4;
                    *reinterpret_cast<float4*>(sh + nxt + i4*4) = ld4(fp + b*8192 + (c+1)*256 + kk);
                }
            }
            #pragma unroll
            for (int b = 0; b < 16; ++b) {
                float4 fv = *reinterpret_cast<const float4*>(sh + cur + b*256 + l*4);
                acc[0][b] += wA[0].x*fv.x + wA[0].y*fv.y + wA[0].z*fv.z + wA[0].w*fv.w;
                acc[1][b] += wA[1].x*fv.x + wA[1].y*fv.y + wA[1].z*fv.z + wA[1].w*fv.w;
            }
            wA[0] = wB[0]; wA[1] = wB[1];
            if (c < 30) {
                wB[0] = ld4(wb + (c+2)*256 + l*4);
                wB[1] = ld4(wb + 8192 + (c+2)*256 + l*4);
            }
            __syncthreads();
        }
        // per-wave 64-lane reduction, stride-33 (conflict-free)
        float* rg = sh + w*2112;
        #pragma unroll
        for (int jj = 0; jj < 2; ++jj)
            #pragma unroll
            for (int b = 0; b < 16; ++b) rg[l*33 + jj*16 + b] = acc[jj][b];
        __syncthreads();
        if (tid < 128) {
            int w2 = tid >> 5, r = tid & 31, jj = r >> 4, b = r & 15;
            const float* rg2 = sh + w2*2112;
            float sum = 0.0f;
            for (int l2 = 0; l2 < 64; ++l2) sum += rg2[l2*33 + r];
            int j = jb*8 + w2*2 + jj;
            int gi = off_m4 + b*1024 + j;
            float m = ws[gi], o = spk(m);
            float mn = m + sum - o;
            ws[gi] = mn;
            ws[off_o4 + wp*M4N + b*1024 + j] = spk(mn);
        }
    } else if (bid < 640) {
        // ---- encoder (redundant) + conv1 + LIF(m1) + pooled next-spike ----
        int bb = bid - 384;
        int b = bb >> 4, tile = bb & 15;
        int ty = tile >> 2, tx = tile & 3;
        int y0 = ty*8, x0 = tx*8;
        const float* vin  = ws + off_v + rp*VS + b*3072;
        float*       vout = ws + off_v + wp*VS + b*3072;
        const float* sin_ = ws + off_s + rp*VS + b*3072;
        float*       sout = ws + off_s + wp*VS + b*3072;
        const float* xin  = x + b*3072;
        float* sl = sh; // [3][10][12]
        for (int idx = tid; idx < 300; idx += 256) {
            int ci = idx/100, r2 = idx%100, rr = r2/10, cc = r2%10;
            int yy = y0 - 1 + rr, xx = x0 - 1 + cc;
            float sv = 0.0f;
            if ((unsigned)yy < 32u && (unsigned)xx < 32u) {
                int g = ci*1024 + yy*32 + xx;
                float vn = vin[g] + xin[g] - sin_[g];
                sv = vn > 1.0f ? 1.0f : 0.0f;
                if (yy >= y0 && yy < y0+8 && xx >= x0 && xx < x0+8) { vout[g] = vn; sout[g] = sv; }
            }
            sl[(ci*10 + rr)*12 + cc] = sv;
        }
        __syncthreads();
        int tl = tid & 15, cog = tid >> 4;
        int py = (tl >> 2)*2, px = (tl & 3)*2;
        for (int cl = 0; cl < 4; ++cl) {
            int co = cog*4 + cl;
            const float* wtp = ws + off_w1r + co*36;
            float a00=0,a01=0,a10=0,a11=0;
            #pragma unroll
            for (int ci = 0; ci < 3; ++ci) {
                float4 w0 = ld4(wtp + ci*12), w1 = ld4(wtp + ci*12 + 4), w2 = ld4(wtp + ci*12 + 8);
                float wdl[3][3] = {{w0.x,w0.y,w0.z},{w1.x,w1.y,w1.z},{w2.x,w2.y,w2.z}};
                #pragma unroll
                for (int dy = 0; dy < 3; ++dy)
                    #pragma unroll
                    for (int dx = 0; dx < 3; ++dx) {
                        float wvv = wdl[dy][dx];
                        const float* rsl = sl + (ci*10 + py + dy)*12 + px + dx;
                        a00 += rsl[0]  * wvv; a01 += rsl[1]  * wvv;
                        a10 += rsl[12] * wvv; a11 += rsl[13] * wvv;
                    }
            }
            int gy = y0 + py, gx = x0 + px;
            float accs[2][2] = {{a00,a01},{a10,a11}};
            float pooled = 0.0f;
            #pragma unroll
            for (int iy = 0; iy < 2; ++iy)
                #pragma unroll
                for (int ix = 0; ix < 2; ++ix) {
                    int gm = off_m1 + ((b*64 + co)*32 + gy + iy)*32 + gx + ix;
                    float m = ws[gm], o = spk(m);
                    float mn = m + accs[iy][ix] - o;
                    ws[gm] = mn;
                    pooled += spk(mn);
                }
            ws[off_o1p + wp*O1PN + ((b*64 + co)*18 + (gy>>1) + 1)*20 + (gx>>1) + 1] = pooled*0.25f;
        }
    } else if (bid < 896) {
        // ---- fc2 1024->1024 + LIF(m5); 256 blocks x 4 cols, 64-lane K-split ----
        int jb = bid - 640;
        int jg = tid >> 6, l = tid & 63;
        int j  = jb*4 + jg;
        const float* op = ws + off_o4 + rp*M4N;
        const float* wr = L2 + j*1024;
        float acc[16] = {};
        float4 wv[4];
        #pragma unroll
        for (int u = 0; u < 4; ++u) wv[u] = ld4(wr + u*256 + l*4);
        #pragma unroll
        for (int u = 0; u < 4; ++u) {
            int k = u*256 + l*4;
            #pragma unroll
            for (int b = 0; b < 16; ++b) {
                float4 fv = ld4(op + b*1024 + k);
                acc[b] += wv[u].x*fv.x + wv[u].y*fv.y + wv[u].z*fv.z + wv[u].w*fv.w;
            }
        }
        int r = jg*64 + l;
        #pragma unroll
        for (int b = 0; b < 16; ++b) sh[r*17 + b] = acc[b];
        __syncthreads();
        {
            int p = tid >> 2, q = tid & 3;
            float s2 = 0.0f;
            int rb2 = (p >> 4)*64 + q*16, col = p & 15;
            #pragma unroll
            for (int t2 = 0; t2 < 16; ++t2) s2 += sh[(rb2 + t2)*17 + col];
            sh[4352 + tid] = s2;
        }
        __syncthreads();
        if (tid < 64) {
            float sum = sh[4352 + tid*4] + sh[4352 + tid*4 + 1]
                      + sh[4352 + tid*4 + 2] + sh[4352 + tid*4 + 3];
            int jg2 = tid >> 4, b = tid & 15;
            int jj = jb*4 + jg2;
            int gi = off_m5 + b*1024 + jj;
            float m = ws[gi], o = spk(m);
            float mn = m + sum - o;
            ws[gi] = mn;
            ws[off_o5 + wp*M5N + b*1024 + jj] = spk(mn);
        }
    } else {
        // ---- fc3 1024->10, accumulate output membrane ----
        if (tid < 160) {
            int b = tid/10, c = tid - b*10;
            const float* op = ws + off_o5 + rp*M5N + b*1024;
            const float* wr = L3 + c*1024;
            float sum = 0.0f;
            for (int k = 0; k < 1024; k += 4) {
                float4 a = ld4(op + k), wvv = ld4(wr + k);
                sum += a.x*wvv.x + a.y*wvv.y + a.z*wvv.z + a.w*wvv.w;
            }
            out[b*10 + c] += sum;
        }
    }
}

extern "C" void kernel_launch(void* const* d_in, const int* in_sizes, int n_in,
                              void* d_out, int out_size, void* d_ws, size_t ws_size,
                              hipStream_t stream) {
    const float* x  = (const float*)d_in[0];
    const float* W1 = (const float*)d_in[1];
    const float* W2 = (const float*)d_in[2];
    const float* W3 = (const float*)d_in[3];
    const float* L1 = (const float*)d_in[4];
    const float* L2 = (const float*)d_in[5];
    const float* L3 = (const float*)d_in[6];
    float* out = (float*)d_out;
    float* ws  = (float*)d_ws;

    init_k<<<1024, 256, 0, stream>>>(W1, W2, W3, ws, out);
    for (int t = 0; t < 20; ++t)
        step_k<<<897, 256, 0, stream>>>(x, L1, L2, L3, ws, out, t);
}